// Round 5
// baseline (584.556 us; speedup 1.0000x reference)
//
#include <hip/hip_runtime.h>
#include <hip/hip_bf16.h>
#include <math.h>

#define CAP 64   // col slots per node (real edges only; self-loop implicit)

// ---------------- adjacency fill: 1 edge per thread, deg pre-zeroed ----------------

__global__ void fill_fixed_kernel(const int* __restrict__ ei, int* __restrict__ deg,
                                  int* __restrict__ col, int E) {
    int idx = blockIdx.x * blockDim.x + threadIdx.x;
    if (idx >= E) return;
    int s = ei[idx];
    int d = ei[E + idx];
    int pos = atomicAdd(&deg[d], 1);
    if (pos < CAP - 1) col[(size_t)d * CAP + pos] = s;   // slot CAP-1 reserved for self-loop lane
}

// ---------------- layer-0 dense: h = x @ W, es = h.a_s, ed = h.a_d ----------------
// lane = output feature; W column in VGPRs; x rows loaded coalesced then
// broadcast via v_readlane into v_fma's SGPR operand slot.

__device__ __forceinline__ float rl(float v, int l) {
    return __int_as_float(__builtin_amdgcn_readlane(__float_as_int(v), l));
}

template<int K>
__global__ __launch_bounds__(256, 2) void gemm_h_kernel(
        const float* __restrict__ x, const float* __restrict__ W,
        const float* __restrict__ a_s, const float* __restrict__ a_d,
        float* __restrict__ h, float* __restrict__ es, float* __restrict__ ed, int n) {
    constexpr int K4 = K / 4;
    constexpr int RW = 8;
    constexpr int NLD = RW * K4 / 64;

    int tid = threadIdx.x;
    int lane = tid & 63;
    float w[K];
    #pragma unroll
    for (int k = 0; k < K; ++k) w[k] = W[k * 64 + lane];
    float asv = a_s[lane];
    float adv = a_d[lane];

    int wid = (blockIdx.x * 256 + tid) >> 6;
    int nwaves = (gridDim.x * 256) >> 6;
    int ngroups = (n + RW - 1) / RW;

    for (int g = wid; g < ngroups; g += nwaves) {
        int r0 = g * RW;
        float4 xr[NLD];
        #pragma unroll
        for (int i = 0; i < NLD; ++i) {
            int flat = i * 64 + lane;
            int r = flat / K4, k4 = flat % K4;
            int row = r0 + r; if (row >= n) row = n - 1;
            xr[i] = *(const float4*)(x + (size_t)row * K + k4 * 4);
        }
        #pragma unroll
        for (int r = 0; r < RW; ++r) {
            float acc0 = 0.f, acc1 = 0.f, acc2 = 0.f, acc3 = 0.f;
            #pragma unroll
            for (int k4 = 0; k4 < K4; ++k4) {
                int flat = r * K4 + k4;
                int reg = flat >> 6, src = flat & 63;
                float4 v = xr[reg];
                acc0 = fmaf(rl(v.x, src), w[4 * k4 + 0], acc0);
                acc1 = fmaf(rl(v.y, src), w[4 * k4 + 1], acc1);
                acc2 = fmaf(rl(v.z, src), w[4 * k4 + 2], acc2);
                acc3 = fmaf(rl(v.w, src), w[4 * k4 + 3], acc3);
            }
            int row = r0 + r;
            float a = (acc0 + acc1) + (acc2 + acc3);
            float ps = a * asv;
            float pd = a * adv;
            #pragma unroll
            for (int off = 32; off; off >>= 1) {
                ps += __shfl_xor(ps, off);
                pd += __shfl_xor(pd, off);
            }
            if (row < n) {
                h[(size_t)row * 64 + lane] = a;
                if (lane == 0) { es[row] = ps; ed[row] = pd; }
            }
        }
    }
}

// ---------------- fused aggregate + next-layer GEMM ----------------
// Aggregates layer l (softmax over incoming + self-loop, bias, relu) giving
// out[lane] for the wave's node, then immediately computes
// hnext[lane] = sum_k out[k] * Wn[k][lane]  (64 readlane+fma),
// es/ed for the next layer, writing the ping-pong buffers.

__global__ __launch_bounds__(256, 4) void agg_gemm_kernel(
        const float* __restrict__ h, const float* __restrict__ es, const float* __restrict__ ed,
        const int* __restrict__ deg, const int* __restrict__ col,
        const float* __restrict__ bias,
        const float* __restrict__ Wn, const float* __restrict__ asn,
        const float* __restrict__ adn,
        float* __restrict__ hn, float* __restrict__ esn, float* __restrict__ edn, int n) {
    int tid = threadIdx.x;
    int lane = tid & 63;
    float w[64];
    #pragma unroll
    for (int k = 0; k < 64; ++k) w[k] = Wn[k * 64 + lane];

    int node = (blockIdx.x * 256 + tid) >> 6;
    if (node >= n) return;
    int cr = deg[node]; if (cr > CAP - 1) cr = CAP - 1;   // real edges
    int cnt = cr + 1;                                     // + self-loop
    float edi = ed[node];

    int s = 0;
    float e = -INFINITY;
    if (lane < cr) {
        s = col[(size_t)node * CAP + lane];
        float t = es[s] + edi;
        e = (t >= 0.f) ? t : 0.2f * t;
    } else if (lane == cr) {
        s = node;
        float t = es[node] + edi;
        e = (t >= 0.f) ? t : 0.2f * t;
    }
    float m = e;
    #pragma unroll
    for (int off = 32; off; off >>= 1) m = fmaxf(m, __shfl_xor(m, off));
    float p = __expf(e - m);
    float denom = p;
    #pragma unroll
    for (int off = 32; off; off >>= 1) denom += __shfl_xor(denom, off);

    float a0 = 0.f, a1 = 0.f, a2 = 0.f, a3 = 0.f;
    int iters = (cnt + 3) & ~3;
    for (int j = 0; j < iters; j += 4) {
        float p0 = __shfl(p, j + 0); int s0 = __shfl(s, j + 0);
        float p1 = __shfl(p, j + 1); int s1 = __shfl(s, j + 1);
        float p2 = __shfl(p, j + 2); int s2 = __shfl(s, j + 2);
        float p3 = __shfl(p, j + 3); int s3 = __shfl(s, j + 3);
        a0 = fmaf(p0, h[(size_t)s0 * 64 + lane], a0);
        a1 = fmaf(p1, h[(size_t)s1 * 64 + lane], a1);
        a2 = fmaf(p2, h[(size_t)s2 * 64 + lane], a2);
        a3 = fmaf(p3, h[(size_t)s3 * 64 + lane], a3);
    }
    float out = ((a0 + a1) + (a2 + a3)) / denom + bias[lane];
    out = fmaxf(out, 0.f);                                // relu (layers 0..2)

    // fused next-layer GEMM: hnext[lane] = sum_k out[k] * w[k]
    float hnext = 0.f;
    #pragma unroll
    for (int k = 0; k < 64; ++k) hnext = fmaf(rl(out, k), w[k], hnext);

    float ps = hnext * asn[lane];
    float pd = hnext * adn[lane];
    #pragma unroll
    for (int off = 32; off; off >>= 1) {
        ps += __shfl_xor(ps, off);
        pd += __shfl_xor(pd, off);
    }
    hn[(size_t)node * 64 + lane] = hnext;
    if (lane == 0) { esn[node] = ps; edn[node] = pd; }
}

// ---------------- fused aggregate (layer 2) + final projection Wl (64->1) ----------------

__global__ __launch_bounds__(256, 4) void agg_wl_kernel(
        const float* __restrict__ h, const float* __restrict__ es, const float* __restrict__ ed,
        const int* __restrict__ deg, const int* __restrict__ col,
        const float* __restrict__ bias, const float* __restrict__ Wl,
        float* __restrict__ hl, int n) {
    int tid = threadIdx.x;
    int lane = tid & 63;
    float wl = Wl[lane];

    int node = (blockIdx.x * 256 + tid) >> 6;
    if (node >= n) return;
    int cr = deg[node]; if (cr > CAP - 1) cr = CAP - 1;
    int cnt = cr + 1;
    float edi = ed[node];

    int s = 0;
    float e = -INFINITY;
    if (lane < cr) {
        s = col[(size_t)node * CAP + lane];
        float t = es[s] + edi;
        e = (t >= 0.f) ? t : 0.2f * t;
    } else if (lane == cr) {
        s = node;
        float t = es[node] + edi;
        e = (t >= 0.f) ? t : 0.2f * t;
    }
    float m = e;
    #pragma unroll
    for (int off = 32; off; off >>= 1) m = fmaxf(m, __shfl_xor(m, off));
    float p = __expf(e - m);
    float denom = p;
    #pragma unroll
    for (int off = 32; off; off >>= 1) denom += __shfl_xor(denom, off);

    float a0 = 0.f, a1 = 0.f, a2 = 0.f, a3 = 0.f;
    int iters = (cnt + 3) & ~3;
    for (int j = 0; j < iters; j += 4) {
        float p0 = __shfl(p, j + 0); int s0 = __shfl(s, j + 0);
        float p1 = __shfl(p, j + 1); int s1 = __shfl(s, j + 1);
        float p2 = __shfl(p, j + 2); int s2 = __shfl(s, j + 2);
        float p3 = __shfl(p, j + 3); int s3 = __shfl(s, j + 3);
        a0 = fmaf(p0, h[(size_t)s0 * 64 + lane], a0);
        a1 = fmaf(p1, h[(size_t)s1 * 64 + lane], a1);
        a2 = fmaf(p2, h[(size_t)s2 * 64 + lane], a2);
        a3 = fmaf(p3, h[(size_t)s3 * 64 + lane], a3);
    }
    float out = ((a0 + a1) + (a2 + a3)) / denom + bias[lane];
    out = fmaxf(out, 0.f);

    float ph = out * wl;
    #pragma unroll
    for (int off = 32; off; off >>= 1) ph += __shfl_xor(ph, off);
    if (lane == 0) hl[node] = ph;
}

// ---------------- final layer (OUT=1) aggregation ----------------

__global__ __launch_bounds__(256) void aggregate1_kernel(
        const float* __restrict__ hl, const float* __restrict__ asl,
        const float* __restrict__ adl, const float* __restrict__ bl,
        const int* __restrict__ deg, const int* __restrict__ col,
        float* __restrict__ out, int n) {
    int lane = threadIdx.x & 63;
    int node = (blockIdx.x * blockDim.x + threadIdx.x) >> 6;
    if (node >= n) return;
    float As = asl[0], Ad = adl[0], B = bl[0];
    int cr = deg[node]; if (cr > CAP - 1) cr = CAP - 1;
    float edi = hl[node] * Ad;

    float hs = 0.f;
    float e = -INFINITY;
    if (lane < cr) {
        int s = col[(size_t)node * CAP + lane];
        hs = hl[s];
        float t = fmaf(hs, As, edi);
        e = (t >= 0.f) ? t : 0.2f * t;
    } else if (lane == cr) {
        hs = hl[node];
        float t = fmaf(hs, As, edi);
        e = (t >= 0.f) ? t : 0.2f * t;
    }
    float m = e;
    #pragma unroll
    for (int off = 32; off; off >>= 1) m = fmaxf(m, __shfl_xor(m, off));
    float p = __expf(e - m);
    float d = p;
    float a = p * hs;
    #pragma unroll
    for (int off = 32; off; off >>= 1) {
        d += __shfl_xor(d, off);
        a += __shfl_xor(a, off);
    }
    if (lane == 0) out[node] = a / d + B;
}

// ---------------- launch ----------------

extern "C" void kernel_launch(void* const* d_in, const int* in_sizes, int n_in,
                              void* d_out, int out_size, void* d_ws, size_t ws_size,
                              hipStream_t stream) {
    const float* x0  = (const float*)d_in[0];
    const int*   ei  = (const int*)d_in[1];
    const float* W0  = (const float*)d_in[3];
    const float* as0 = (const float*)d_in[4];
    const float* ad0 = (const float*)d_in[5];
    const float* b0  = (const float*)d_in[6];
    const float* W1  = (const float*)d_in[7];
    const float* as1 = (const float*)d_in[8];
    const float* ad1 = (const float*)d_in[9];
    const float* b1  = (const float*)d_in[10];
    const float* W2  = (const float*)d_in[11];
    const float* as2 = (const float*)d_in[12];
    const float* ad2 = (const float*)d_in[13];
    const float* b2  = (const float*)d_in[14];
    const float* Wl  = (const float*)d_in[15];
    const float* asl = (const float*)d_in[16];
    const float* adl = (const float*)d_in[17];
    const float* bl  = (const float*)d_in[18];

    int n = in_sizes[0] / 128;
    int E = in_sizes[1] / 2;

    char* p = (char*)d_ws;
    auto alloc = [&](size_t bytes) { char* r = p; p += (bytes + 255) & ~255ULL; return r; };
    float* hA  = (float*)alloc((size_t)n * 64 * 4);
    float* hB  = (float*)alloc((size_t)n * 64 * 4);
    int*   col = (int*)alloc((size_t)n * CAP * 4);
    float* esA = (float*)alloc((size_t)n * 4);
    float* edA = (float*)alloc((size_t)n * 4);
    float* esB = (float*)alloc((size_t)n * 4);
    float* edB = (float*)alloc((size_t)n * 4);
    float* hl  = (float*)alloc((size_t)n * 4);
    int*   deg = (int*)alloc((size_t)n * 4);
    (void)ws_size; (void)n_in; (void)out_size;

    int agg_blocks = (n + 3) / 4;

    hipMemsetAsync(deg, 0, (size_t)n * 4, stream);
    fill_fixed_kernel<<<(E + 255) / 256, 256, 0, stream>>>(ei, deg, col, E);

    // layer 0 dense
    gemm_h_kernel<128><<<2048, 256, 0, stream>>>(x0, W0, as0, ad0, hA, esA, edA, n);
    // agg layer0 (+b0, relu) fused with W1 projection -> hB/esB/edB
    agg_gemm_kernel<<<agg_blocks, 256, 0, stream>>>(hA, esA, edA, deg, col, b0,
                                                    W1, as1, ad1, hB, esB, edB, n);
    // agg layer1 (+b1, relu) fused with W2 -> hA/esA/edA
    agg_gemm_kernel<<<agg_blocks, 256, 0, stream>>>(hB, esB, edB, deg, col, b1,
                                                    W2, as2, ad2, hA, esA, edA, n);
    // agg layer2 (+b2, relu) fused with Wl (64->1) -> hl
    agg_wl_kernel<<<agg_blocks, 256, 0, stream>>>(hA, esA, edA, deg, col, b2, Wl, hl, n);
    // final aggregation (OUT=1)
    aggregate1_kernel<<<agg_blocks, 256, 0, stream>>>(hl, asl, adl, bl, deg, col,
                                                      (float*)d_out, n);
}